// Round 1
// baseline (774.349 us; speedup 1.0000x reference)
//
#include <hip/hip_runtime.h>

#define N_NODES 50000
#define N_EDGES 800000
#define D_NODE 128
#define D_HID 64
#define N_GRAPH 128
#define BN_EPS 1e-5f

// ---------------- CSR build ----------------

__global__ void hist_kernel(const int* __restrict__ dst, int* __restrict__ deg, int E) {
    int e = blockIdx.x * 256 + threadIdx.x;
    if (e < E) atomicAdd(&deg[dst[e]], 1);
}

__global__ void scan1_kernel(const int* __restrict__ deg, int* __restrict__ row_ptr,
                             int* __restrict__ blocksum, int n) {
    __shared__ int s[256];
    int i = blockIdx.x * 256 + threadIdx.x;
    int v = (i < n) ? deg[i] : 0;
    s[threadIdx.x] = v;
    __syncthreads();
    for (int off = 1; off < 256; off <<= 1) {
        int t = (threadIdx.x >= off) ? s[threadIdx.x - off] : 0;
        __syncthreads();
        s[threadIdx.x] += t;
        __syncthreads();
    }
    if (i < n) row_ptr[i + 1] = s[threadIdx.x];   // inclusive, pre-offset
    if (threadIdx.x == 255) blocksum[blockIdx.x] = s[255];
}

__global__ void scan2_kernel(int* __restrict__ blocksum, int nb) {
    __shared__ int s[256];
    int v = (threadIdx.x < nb) ? blocksum[threadIdx.x] : 0;
    s[threadIdx.x] = v;
    __syncthreads();
    for (int off = 1; off < 256; off <<= 1) {
        int t = (threadIdx.x >= off) ? s[threadIdx.x - off] : 0;
        __syncthreads();
        s[threadIdx.x] += t;
        __syncthreads();
    }
    if (threadIdx.x < nb) blocksum[threadIdx.x] = s[threadIdx.x] - v;  // exclusive
}

__global__ void scan3_kernel(int* __restrict__ row_ptr, const int* __restrict__ blocksum, int n) {
    int i = blockIdx.x * 256 + threadIdx.x;
    if (i < n) row_ptr[i + 1] += blocksum[blockIdx.x];
    if (i == 0) row_ptr[0] = 0;
}

__global__ void fill_kernel(const int* __restrict__ src, const int* __restrict__ dst,
                            const int* __restrict__ row_ptr, int* __restrict__ pos,
                            int* __restrict__ col, int E) {
    int e = blockIdx.x * 256 + threadIdx.x;
    if (e < E) {
        int d = dst[e];
        int p = atomicAdd(&pos[d], 1);
        col[row_ptr[d] + p] = src[e];
    }
}

// ---------------- aggregation: y[i] = h[i] + sum_{j in nbr(i)} h[j] ----------------

template <int D>
__global__ void agg_kernel(const float* __restrict__ h, const int* __restrict__ row_ptr,
                           const int* __restrict__ col, float* __restrict__ y, int n) {
    int node = blockIdx.x * 4 + (threadIdx.x >> 6);
    int lane = threadIdx.x & 63;
    if (node >= n) return;
    int beg = row_ptr[node], end = row_ptr[node + 1];
    if constexpr (D == 64) {
        float acc = h[(size_t)node * 64 + lane];
        int e = beg;
        for (; e + 4 <= end; e += 4) {
            int s0 = col[e], s1 = col[e + 1], s2 = col[e + 2], s3 = col[e + 3];
            float v0 = h[(size_t)s0 * 64 + lane];
            float v1 = h[(size_t)s1 * 64 + lane];
            float v2 = h[(size_t)s2 * 64 + lane];
            float v3 = h[(size_t)s3 * 64 + lane];
            acc += v0; acc += v1; acc += v2; acc += v3;
        }
        for (; e < end; ++e) acc += h[(size_t)col[e] * 64 + lane];
        y[(size_t)node * 64 + lane] = acc;
    } else {
        float a0 = h[(size_t)node * 128 + lane];
        float a1 = h[(size_t)node * 128 + 64 + lane];
        int e = beg;
        for (; e + 2 <= end; e += 2) {
            int s0 = col[e], s1 = col[e + 1];
            float v00 = h[(size_t)s0 * 128 + lane];
            float v01 = h[(size_t)s0 * 128 + 64 + lane];
            float v10 = h[(size_t)s1 * 128 + lane];
            float v11 = h[(size_t)s1 * 128 + 64 + lane];
            a0 += v00; a1 += v01; a0 += v10; a1 += v11;
        }
        for (; e < end; ++e) {
            int s = col[e];
            a0 += h[(size_t)s * 128 + lane];
            a1 += h[(size_t)s * 128 + 64 + lane];
        }
        y[(size_t)node * 128 + lane] = a0;
        y[(size_t)node * 128 + 64 + lane] = a1;
    }
}

// ---------------- fused MLP: h = relu(bnO(relu(bnI(y@W1+b1))@W2+b2)) ----------------
// block = 128 threads, tile = 32 nodes.

template <int DIN>
__launch_bounds__(128)
__global__ void mlp_kernel(const float* __restrict__ y, float* __restrict__ hout,
                           const float* __restrict__ W1, const float* __restrict__ b1,
                           const float* __restrict__ ig, const float* __restrict__ ib,
                           const float* __restrict__ im, const float* __restrict__ iv,
                           const float* __restrict__ W2, const float* __restrict__ b2,
                           const float* __restrict__ og, const float* __restrict__ ob,
                           const float* __restrict__ om, const float* __restrict__ ov,
                           int n) {
    __shared__ float y_lds[32 * DIN];
    __shared__ float z_lds[32 * 128];
    const int tid = threadIdx.x;
    const int node0 = blockIdx.x * 32;
    const int nvalid = min(32, n - node0);
    const int limit = nvalid * DIN;

    // stage y tile (rows are contiguous in global)
    for (int idx = tid; idx < 32 * DIN; idx += 128)
        y_lds[idx] = (idx < limit) ? y[(size_t)node0 * DIN + idx] : 0.f;
    __syncthreads();

    // GEMM1: channels kp, kp+1 ; nodes nh..nh+15
    const int kp = (tid & 63) * 2;
    const int nh = (tid >> 6) * 16;
    float z0[16], z1[16];
#pragma unroll
    for (int j = 0; j < 16; ++j) { z0[j] = 0.f; z1[j] = 0.f; }

    for (int d4 = 0; d4 < DIN; d4 += 4) {
        float2 w0 = *(const float2*)&W1[(d4 + 0) * 128 + kp];
        float2 w1 = *(const float2*)&W1[(d4 + 1) * 128 + kp];
        float2 w2 = *(const float2*)&W1[(d4 + 2) * 128 + kp];
        float2 w3 = *(const float2*)&W1[(d4 + 3) * 128 + kp];
#pragma unroll
        for (int j = 0; j < 16; ++j) {
            float4 yv = *(const float4*)&y_lds[(nh + j) * DIN + d4];
            z0[j] += yv.x * w0.x + yv.y * w1.x + yv.z * w2.x + yv.w * w3.x;
            z1[j] += yv.x * w0.y + yv.y * w1.y + yv.z * w2.y + yv.w * w3.y;
        }
    }

    // BN1 (folded with b1) + ReLU, write transposed tile to LDS
    {
        float sA0 = ig[kp] * rsqrtf(iv[kp] + BN_EPS);
        float cA0 = (b1[kp] - im[kp]) * sA0 + ib[kp];
        float sA1 = ig[kp + 1] * rsqrtf(iv[kp + 1] + BN_EPS);
        float cA1 = (b1[kp + 1] - im[kp + 1]) * sA1 + ib[kp + 1];
#pragma unroll
        for (int j = 0; j < 16; ++j) {
            float a = fmaxf(z0[j] * sA0 + cA0, 0.f);
            float b = fmaxf(z1[j] * sA1 + cA1, 0.f);
            *(float2*)&z_lds[(nh + j) * 128 + kp] = make_float2(a, b);
        }
    }
    __syncthreads();

    // GEMM2: channels cp, cp+1 ; nodes nq..nq+7
    const int cp = (tid & 31) * 2;
    const int nq = (tid >> 5) * 8;
    float a0[8], a1[8];
#pragma unroll
    for (int j = 0; j < 8; ++j) { a0[j] = 0.f; a1[j] = 0.f; }

    for (int k4 = 0; k4 < 128; k4 += 4) {
        float2 u0 = *(const float2*)&W2[(k4 + 0) * 64 + cp];
        float2 u1 = *(const float2*)&W2[(k4 + 1) * 64 + cp];
        float2 u2 = *(const float2*)&W2[(k4 + 2) * 64 + cp];
        float2 u3 = *(const float2*)&W2[(k4 + 3) * 64 + cp];
#pragma unroll
        for (int j = 0; j < 8; ++j) {
            float4 zv = *(const float4*)&z_lds[(nq + j) * 128 + k4];
            a0[j] += zv.x * u0.x + zv.y * u1.x + zv.z * u2.x + zv.w * u3.x;
            a1[j] += zv.x * u0.y + zv.y * u1.y + zv.z * u2.y + zv.w * u3.y;
        }
    }

    // b2 + outer BN + ReLU + store
    {
        float sB0 = og[cp] * rsqrtf(ov[cp] + BN_EPS);
        float cB0 = (b2[cp] - om[cp]) * sB0 + ob[cp];
        float sB1 = og[cp + 1] * rsqrtf(ov[cp + 1] + BN_EPS);
        float cB1 = (b2[cp + 1] - om[cp + 1]) * sB1 + ob[cp + 1];
#pragma unroll
        for (int j = 0; j < 8; ++j) {
            int node = node0 + nq + j;
            if (node < n) {
                float h0 = fmaxf(a0[j] * sB0 + cB0, 0.f);
                float h1 = fmaxf(a1[j] * sB1 + cB1, 0.f);
                *(float2*)&hout[(size_t)node * 64 + cp] = make_float2(h0, h1);
            }
        }
    }
}

// ---------------- pooling (batch is sorted) ----------------

__global__ void pool_kernel(const float* __restrict__ h, const int* __restrict__ batch,
                            float* __restrict__ sums, int* __restrict__ cnt, int n) {
    int lane = threadIdx.x & 63;
    int n0 = blockIdx.x * 256;
    if (n0 >= n) return;
    int n1 = min(n0 + 256, n);
    float acc = 0.f;
    int c = 0;
    int g_cur = batch[n0];
    for (int i = n0; i < n1; ++i) {
        int g = batch[i];
        if (g != g_cur) {
            atomicAdd(&sums[g_cur * 64 + lane], acc);
            if (lane == 0) atomicAdd(&cnt[g_cur], c);
            acc = 0.f; c = 0; g_cur = g;
        }
        acc += h[(size_t)i * 64 + lane];
        c++;
    }
    atomicAdd(&sums[g_cur * 64 + lane], acc);
    if (lane == 0) atomicAdd(&cnt[g_cur], c);
}

__global__ void finalize_kernel(const float* __restrict__ sums, const int* __restrict__ cnt,
                                float* __restrict__ out) {
    int i = blockIdx.x * 256 + threadIdx.x;
    if (i < N_GRAPH * 64) {
        float c = (float)cnt[i >> 6];
        out[i] = sums[i] / fmaxf(c, 1.f);
    }
}

// ---------------- launcher ----------------

extern "C" void kernel_launch(void* const* d_in, const int* in_sizes, int n_in,
                              void* d_out, int out_size, void* d_ws, size_t ws_size,
                              hipStream_t stream) {
    const float* x    = (const float*)d_in[0];
    const int*  ei    = (const int*)d_in[1];
    const int*  batch = (const int*)d_in[2];
    const float* w1_0 = (const float*)d_in[3];
    const float* b1_0 = (const float*)d_in[4];
    const float* ig0  = (const float*)d_in[5];
    const float* ib0  = (const float*)d_in[6];
    const float* im0  = (const float*)d_in[7];
    const float* iv0  = (const float*)d_in[8];
    const float* w2_0 = (const float*)d_in[9];
    const float* b2_0 = (const float*)d_in[10];
    const float* W1s  = (const float*)d_in[11];
    const float* b1s  = (const float*)d_in[12];
    const float* IG   = (const float*)d_in[13];
    const float* IB   = (const float*)d_in[14];
    const float* IM   = (const float*)d_in[15];
    const float* IV   = (const float*)d_in[16];
    const float* W2s  = (const float*)d_in[17];
    const float* b2s  = (const float*)d_in[18];
    const float* OG   = (const float*)d_in[19];
    const float* OB   = (const float*)d_in[20];
    const float* OM   = (const float*)d_in[21];
    const float* OV   = (const float*)d_in[22];
    float* out = (float*)d_out;

    const int N = N_NODES, E = N_EDGES;
    const int* src = ei;
    const int* dst = ei + E;

    char* ws = (char*)d_ws;
    size_t off = 0;
    auto alloc = [&](size_t bytes) -> void* {
        void* p = ws + off;
        off += (bytes + 255) & ~(size_t)255;
        return p;
    };
    int*   row_ptr  = (int*)alloc((N + 1) * sizeof(int));
    int*   deg      = (int*)alloc(N * sizeof(int));
    int*   pos      = (int*)alloc(N * sizeof(int));
    int*   blocksum = (int*)alloc(256 * sizeof(int));
    int*   col      = (int*)alloc((size_t)E * sizeof(int));
    float* ybuf     = (float*)alloc((size_t)N * 128 * sizeof(float));
    float* hbuf     = (float*)alloc((size_t)N * 64 * sizeof(float));
    float* sums     = (float*)alloc(N_GRAPH * 64 * sizeof(float));
    int*   cnt      = (int*)alloc(N_GRAPH * sizeof(int));

    const int NB = (N + 255) / 256;   // 196
    const int EB = (E + 255) / 256;   // 3125

    hipMemsetAsync(deg, 0, N * sizeof(int), stream);
    hipMemsetAsync(pos, 0, N * sizeof(int), stream);
    hipMemsetAsync(sums, 0, N_GRAPH * 64 * sizeof(float), stream);
    hipMemsetAsync(cnt, 0, N_GRAPH * sizeof(int), stream);

    // CSR build (edge_index is layer-invariant: build once)
    hist_kernel<<<EB, 256, 0, stream>>>(dst, deg, E);
    scan1_kernel<<<NB, 256, 0, stream>>>(deg, row_ptr, blocksum, N);
    scan2_kernel<<<1, 256, 0, stream>>>(blocksum, NB);
    scan3_kernel<<<NB, 256, 0, stream>>>(row_ptr, blocksum, N);
    fill_kernel<<<EB, 256, 0, stream>>>(src, dst, row_ptr, pos, col, E);

    const int AGB = (N + 3) / 4;      // 12500 blocks (wave per node)
    const int MGB = (N + 31) / 32;    // 1563 blocks

    // layer 0 (input dim 128)
    agg_kernel<128><<<AGB, 256, 0, stream>>>(x, row_ptr, col, ybuf, N);
    mlp_kernel<128><<<MGB, 128, 0, stream>>>(ybuf, hbuf, w1_0, b1_0, ig0, ib0, im0, iv0,
                                             w2_0, b2_0, OG, OB, OM, OV, N);
    // layers 1..4 (input dim 64)
    for (int i = 0; i < 4; ++i) {
        agg_kernel<64><<<AGB, 256, 0, stream>>>(hbuf, row_ptr, col, ybuf, N);
        mlp_kernel<64><<<MGB, 128, 0, stream>>>(ybuf, hbuf,
                                                W1s + (size_t)i * 64 * 128, b1s + i * 128,
                                                IG + i * 128, IB + i * 128,
                                                IM + i * 128, IV + i * 128,
                                                W2s + (size_t)i * 128 * 64, b2s + i * 64,
                                                OG + (i + 1) * 64, OB + (i + 1) * 64,
                                                OM + (i + 1) * 64, OV + (i + 1) * 64, N);
    }

    pool_kernel<<<NB, 64, 0, stream>>>(hbuf, batch, sums, cnt, N);
    finalize_kernel<<<32, 256, 0, stream>>>(sums, cnt, out);
}

// Round 2
// 576.590 us; speedup vs baseline: 1.3430x; 1.3430x over previous
//
#include <hip/hip_runtime.h>
#include <stdint.h>

#define NN 50000
#define NE 800000
#define NG 128
#define BN_EPS 1e-5f

typedef __attribute__((ext_vector_type(8))) __bf16 bf16x8;
typedef __attribute__((ext_vector_type(8))) unsigned short ushort8;
typedef __attribute__((ext_vector_type(4))) float floatx4;

__device__ inline unsigned short f2bf(float f) {
    union { float f; unsigned u; } x; x.f = f;
    unsigned u = x.u;
    return (unsigned short)((u + 0x7fffu + ((u >> 16) & 1u)) >> 16);
}
__device__ inline float bflo(unsigned u) {
    union { unsigned u; float f; } x; x.u = u << 16; return x.f;
}
__device__ inline float bfhi(unsigned u) {
    union { unsigned u; float f; } x; x.u = u & 0xffff0000u; return x.f;
}
__device__ inline bf16x8 as_bf(ushort8 u) {
    union { ushort8 u; bf16x8 b; } x; x.u = u; return x.b;
}

// ---------------- CSR build ----------------

__global__ void hist_kernel(const int* __restrict__ dst, int* __restrict__ deg, int E) {
    int e = blockIdx.x * 256 + threadIdx.x;
    if (e < E) atomicAdd(&deg[dst[e]], 1);
}

__global__ void scan1_kernel(const int* __restrict__ deg, int* __restrict__ row_ptr,
                             int* __restrict__ blocksum, int n) {
    __shared__ int s[256];
    int i = blockIdx.x * 256 + threadIdx.x;
    int v = (i < n) ? deg[i] : 0;
    s[threadIdx.x] = v;
    __syncthreads();
    for (int off = 1; off < 256; off <<= 1) {
        int t = (threadIdx.x >= off) ? s[threadIdx.x - off] : 0;
        __syncthreads();
        s[threadIdx.x] += t;
        __syncthreads();
    }
    if (i < n) row_ptr[i + 1] = s[threadIdx.x];
    if (threadIdx.x == 255) blocksum[blockIdx.x] = s[255];
}

__global__ void scan2_kernel(int* __restrict__ blocksum, int nb) {
    __shared__ int s[256];
    int v = (threadIdx.x < nb) ? blocksum[threadIdx.x] : 0;
    s[threadIdx.x] = v;
    __syncthreads();
    for (int off = 1; off < 256; off <<= 1) {
        int t = (threadIdx.x >= off) ? s[threadIdx.x - off] : 0;
        __syncthreads();
        s[threadIdx.x] += t;
        __syncthreads();
    }
    if (threadIdx.x < nb) blocksum[threadIdx.x] = s[threadIdx.x] - v;
}

__global__ void scan3_kernel(int* __restrict__ row_ptr, const int* __restrict__ blocksum, int n) {
    int i = blockIdx.x * 256 + threadIdx.x;
    if (i < n) row_ptr[i + 1] += blocksum[blockIdx.x];
    if (i == 0) row_ptr[0] = 0;
}

__global__ void fill_kernel(const int* __restrict__ src, const int* __restrict__ dst,
                            const int* __restrict__ row_ptr, int* __restrict__ pos,
                            int* __restrict__ col, int E) {
    int e = blockIdx.x * 256 + threadIdx.x;
    if (e < E) {
        int d = dst[e];
        int p = atomicAdd(&pos[d], 1);
        col[row_ptr[d] + p] = src[e];
    }
}

// ---------------- weight prep: transpose + bf16 cvt + BN fold ----------------

struct PrepArgs {
    const float* w1[5]; const float* w2[5];
    const float* b1[5]; const float* ig[5]; const float* ib[5];
    const float* im[5]; const float* iv[5]; const float* b2[5];
    const float* og; const float* ob; const float* om; const float* ov;
    unsigned short* w1t[5]; unsigned short* w2t[5];
    float* s1[5]; float* c1[5]; float* s2[5]; float* c2[5];
};

__global__ void prep_kernel(PrepArgs p) {
    int layer = blockIdx.x;
    int K = (layer == 0) ? 128 : 64;
    int kshift = (layer == 0) ? 7 : 6;
    const float* w1 = p.w1[layer];
    unsigned short* w1t = p.w1t[layer];
    for (int idx = threadIdx.x; idx < 128 * K; idx += blockDim.x) {
        int c = idx >> kshift, k = idx & (K - 1);
        w1t[idx] = f2bf(w1[k * 128 + c]);       // w1t[c*K+k]
    }
    const float* w2 = p.w2[layer];
    unsigned short* w2t = p.w2t[layer];
    for (int idx = threadIdx.x; idx < 64 * 128; idx += blockDim.x) {
        int c = idx >> 7, k = idx & 127;
        w2t[idx] = f2bf(w2[k * 64 + c]);        // w2t[c*128+k]
    }
    if (threadIdx.x < 128) {
        int ch = threadIdx.x;
        float s = p.ig[layer][ch] * rsqrtf(p.iv[layer][ch] + BN_EPS);
        p.s1[layer][ch] = s;
        p.c1[layer][ch] = (p.b1[layer][ch] - p.im[layer][ch]) * s + p.ib[layer][ch];
        if (ch < 64) {
            float s2v = p.og[layer * 64 + ch] * rsqrtf(p.ov[layer * 64 + ch] + BN_EPS);
            p.s2[layer][ch] = s2v;
            p.c2[layer][ch] = (p.b2[layer][ch] - p.om[layer * 64 + ch]) * s2v + p.ob[layer * 64 + ch];
        }
    }
}

// ---------------- aggregation ----------------

// layer 0: x fp32 [N][128] -> y bf16 [N][128]; wave per node, lane = ch-pair
__global__ void agg0_kernel(const float* __restrict__ x, const int* __restrict__ rp,
                            const int* __restrict__ col, unsigned short* __restrict__ y, int n) {
    int node = blockIdx.x * 4 + (threadIdx.x >> 6);
    int l = threadIdx.x & 63;
    if (node >= n) return;
    const float2* xr = (const float2*)x;        // [N][64] float2
    float2 a = xr[(size_t)node * 64 + l];
    int beg = rp[node], end = rp[node + 1];
    int e = beg;
    for (; e + 2 <= end; e += 2) {
        int s0 = col[e], s1 = col[e + 1];
        float2 v0 = xr[(size_t)s0 * 64 + l];
        float2 v1 = xr[(size_t)s1 * 64 + l];
        a.x += v0.x; a.y += v0.y; a.x += v1.x; a.y += v1.y;
    }
    if (e < end) { float2 v = xr[(size_t)col[e] * 64 + l]; a.x += v.x; a.y += v.y; }
    ((unsigned*)y)[(size_t)node * 64 + l] = (unsigned)f2bf(a.x) | ((unsigned)f2bf(a.y) << 16);
}

// layers 1..4: h bf16 [N][64] -> y bf16 [N][64]; half-wave per node, lane = ch-pair
__global__ void agg1_kernel(const unsigned short* __restrict__ h, const int* __restrict__ rp,
                            const int* __restrict__ col, unsigned short* __restrict__ y, int n) {
    int node = blockIdx.x * 8 + (threadIdx.x >> 5);
    int l = threadIdx.x & 31;
    if (node >= n) return;
    const unsigned* hr = (const unsigned*)h;    // [N][32] packed
    unsigned u = hr[(size_t)node * 32 + l];
    float a0 = bflo(u), a1 = bfhi(u);
    int beg = rp[node], end = rp[node + 1];
    int e = beg;
    for (; e + 2 <= end; e += 2) {
        unsigned v0 = hr[(size_t)col[e] * 32 + l];
        unsigned v1 = hr[(size_t)col[e + 1] * 32 + l];
        a0 += bflo(v0); a1 += bfhi(v0);
        a0 += bflo(v1); a1 += bfhi(v1);
    }
    if (e < end) { unsigned v = hr[(size_t)col[e] * 32 + l]; a0 += bflo(v); a1 += bfhi(v); }
    ((unsigned*)y)[(size_t)node * 32 + l] = (unsigned)f2bf(a0) | ((unsigned)f2bf(a1) << 16);
}

// ---------------- fused MLP via MFMA ----------------
// 64-node tile, 4 waves; wave w owns nodes [w*16, w*16+16). LDS only for
// per-wave transposes. Z layout [64][132] f32 (stride 132 -> 2-way banks, free).

template <int K>
__launch_bounds__(256, 3)
__global__ void mlp_mfma(const unsigned short* __restrict__ yb, unsigned short* __restrict__ hb,
                         const unsigned short* __restrict__ w1t,  // [128][K] bf16
                         const unsigned short* __restrict__ w2t,  // [64][128] bf16
                         const float* __restrict__ s1, const float* __restrict__ c1,
                         const float* __restrict__ s2, const float* __restrict__ c2,
                         int n) {
    __shared__ float zl[64 * 132];
    const int tid = threadIdx.x;
    const int w = tid >> 6;
    const int l = tid & 63;
    const int l15 = l & 15, lg = l >> 4;
    const int node0 = blockIdx.x * 64;

    // ---- GEMM1: Z[64x128] = Y[64xK] @ W1[Kx128]
    const int arow = node0 + w * 16 + l15;
    const int arow_c = min(arow, n - 1);
    bf16x8 afr[K / 32];
#pragma unroll
    for (int ks = 0; ks < K / 32; ++ks)
        afr[ks] = as_bf(*(const ushort8*)(yb + (size_t)arow_c * K + ks * 32 + lg * 8));

#pragma unroll
    for (int cc = 0; cc < 8; ++cc) {
        floatx4 acc = {0.f, 0.f, 0.f, 0.f};
#pragma unroll
        for (int ks = 0; ks < K / 32; ++ks) {
            bf16x8 bfr = as_bf(*(const ushort8*)(w1t + (size_t)(cc * 16 + l15) * K + ks * 32 + lg * 8));
            acc = __builtin_amdgcn_mfma_f32_16x16x32_bf16(afr[ks], bfr, acc, 0, 0, 0);
        }
        int ch = cc * 16 + l15;
        float s = s1[ch], c = c1[ch];
#pragma unroll
        for (int r = 0; r < 4; ++r) {
            int row = w * 16 + lg * 4 + r;
            zl[row * 132 + ch] = fmaxf(acc[r] * s + c, 0.f);
        }
    }
    __syncthreads();

    // ---- GEMM2: H[64x64] = Zr[64x128] @ W2[128x64]
    floatx4 acc2[4];
#pragma unroll
    for (int ct = 0; ct < 4; ++ct) acc2[ct] = (floatx4){0.f, 0.f, 0.f, 0.f};

#pragma unroll
    for (int ks = 0; ks < 4; ++ks) {
        const float* zp = &zl[(w * 16 + l15) * 132 + ks * 32 + lg * 8];
        float4 za = *(const float4*)zp;
        float4 zb = *(const float4*)(zp + 4);
        ushort8 au;
        au[0] = f2bf(za.x); au[1] = f2bf(za.y); au[2] = f2bf(za.z); au[3] = f2bf(za.w);
        au[4] = f2bf(zb.x); au[5] = f2bf(zb.y); au[6] = f2bf(zb.z); au[7] = f2bf(zb.w);
        bf16x8 a2 = as_bf(au);
#pragma unroll
        for (int ct = 0; ct < 4; ++ct) {
            bf16x8 b2 = as_bf(*(const ushort8*)(w2t + (size_t)(ct * 16 + l15) * 128 + ks * 32 + lg * 8));
            acc2[ct] = __builtin_amdgcn_mfma_f32_16x16x32_bf16(a2, b2, acc2[ct], 0, 0, 0);
        }
    }
    __syncthreads();   // everyone done reading zl before we overwrite with H

    // ---- BN2 + ReLU -> per-wave H region (stride 68), then coalesced bf16 store
    float* Hp = zl + w * 2112;   // wave-private 16x132 region
#pragma unroll
    for (int ct = 0; ct < 4; ++ct) {
        int ch = ct * 16 + l15;
        float s = s2[ch], c = c2[ch];
#pragma unroll
        for (int r = 0; r < 4; ++r)
            Hp[(lg * 4 + r) * 68 + ch] = fmaxf(acc2[ct][r] * s + c, 0.f);
    }
    __syncthreads();   // cross-lane handoff within wave region

    int nr = l >> 2, ch0 = (l & 3) * 16;
    int node = node0 + w * 16 + nr;
    if (node < n) {
        const float* q = Hp + nr * 68 + ch0;
        ushort8 u0, u1;
#pragma unroll
        for (int j = 0; j < 8; ++j) u0[j] = f2bf(q[j]);
#pragma unroll
        for (int j = 0; j < 8; ++j) u1[j] = f2bf(q[8 + j]);
        *(ushort8*)(hb + (size_t)node * 64 + ch0) = u0;
        *(ushort8*)(hb + (size_t)node * 64 + ch0 + 8) = u1;
    }
}

// ---------------- pooling (batch sorted) ----------------

__global__ void pool_kernel(const unsigned short* __restrict__ h, const int* __restrict__ batch,
                            float* __restrict__ sums, int* __restrict__ cnt, int n) {
    int l = threadIdx.x;           // 0..31, 2 ch per lane
    int n0 = blockIdx.x * 256;
    if (n0 >= n) return;
    int n1 = min(n0 + 256, n);
    const unsigned* hr = (const unsigned*)h;
    float a0 = 0.f, a1 = 0.f; int c = 0;
    int g_cur = batch[n0];
    for (int i = n0; i < n1; ++i) {
        int g = batch[i];
        if (g != g_cur) {
            atomicAdd(&sums[g_cur * 64 + 2 * l], a0);
            atomicAdd(&sums[g_cur * 64 + 2 * l + 1], a1);
            if (l == 0) atomicAdd(&cnt[g_cur], c);
            a0 = a1 = 0.f; c = 0; g_cur = g;
        }
        unsigned u = hr[(size_t)i * 32 + l];
        a0 += bflo(u); a1 += bfhi(u);
        c++;
    }
    atomicAdd(&sums[g_cur * 64 + 2 * l], a0);
    atomicAdd(&sums[g_cur * 64 + 2 * l + 1], a1);
    if (l == 0) atomicAdd(&cnt[g_cur], c);
}

__global__ void finalize_kernel(const float* __restrict__ sums, const int* __restrict__ cnt,
                                float* __restrict__ out) {
    int i = blockIdx.x * 256 + threadIdx.x;
    if (i < NG * 64) {
        float c = (float)cnt[i >> 6];
        out[i] = sums[i] / fmaxf(c, 1.f);
    }
}

// ---------------- launcher ----------------

extern "C" void kernel_launch(void* const* d_in, const int* in_sizes, int n_in,
                              void* d_out, int out_size, void* d_ws, size_t ws_size,
                              hipStream_t stream) {
    const float* x    = (const float*)d_in[0];
    const int*  ei    = (const int*)d_in[1];
    const int*  batch = (const int*)d_in[2];
    const float* w1_0 = (const float*)d_in[3];
    const float* b1_0 = (const float*)d_in[4];
    const float* ig0  = (const float*)d_in[5];
    const float* ib0  = (const float*)d_in[6];
    const float* im0  = (const float*)d_in[7];
    const float* iv0  = (const float*)d_in[8];
    const float* w2_0 = (const float*)d_in[9];
    const float* b2_0 = (const float*)d_in[10];
    const float* W1s  = (const float*)d_in[11];
    const float* b1s  = (const float*)d_in[12];
    const float* IG   = (const float*)d_in[13];
    const float* IB   = (const float*)d_in[14];
    const float* IM   = (const float*)d_in[15];
    const float* IV   = (const float*)d_in[16];
    const float* W2s  = (const float*)d_in[17];
    const float* b2s  = (const float*)d_in[18];
    const float* OG   = (const float*)d_in[19];
    const float* OB   = (const float*)d_in[20];
    const float* OM   = (const float*)d_in[21];
    const float* OV   = (const float*)d_in[22];
    float* out = (float*)d_out;

    const int N = NN, E = NE;
    const int* src = ei;
    const int* dst = ei + E;

    char* ws = (char*)d_ws;
    size_t off = 0;
    auto alloc = [&](size_t bytes) -> void* {
        void* p = ws + off;
        off += (bytes + 255) & ~(size_t)255;
        return p;
    };
    int*   row_ptr  = (int*)alloc((N + 1) * sizeof(int));
    int*   deg      = (int*)alloc(N * sizeof(int));
    int*   pos      = (int*)alloc(N * sizeof(int));
    int*   blocksum = (int*)alloc(256 * sizeof(int));
    int*   col      = (int*)alloc((size_t)E * sizeof(int));
    unsigned short* ybuf = (unsigned short*)alloc((size_t)N * 128 * 2);
    unsigned short* hbuf = (unsigned short*)alloc((size_t)N * 64 * 2);
    unsigned short* w1t  = (unsigned short*)alloc(49152 * 2);   // 128*128 + 4*128*64
    unsigned short* w2t  = (unsigned short*)alloc(5 * 64 * 128 * 2);
    float* s1 = (float*)alloc(5 * 128 * sizeof(float));
    float* c1 = (float*)alloc(5 * 128 * sizeof(float));
    float* s2 = (float*)alloc(5 * 64 * sizeof(float));
    float* c2 = (float*)alloc(5 * 64 * sizeof(float));
    float* sums = (float*)alloc(NG * 64 * sizeof(float));
    int*   cnt  = (int*)alloc(NG * sizeof(int));

    const int NB = (N + 255) / 256;
    const int EB = (E + 255) / 256;

    hipMemsetAsync(deg, 0, N * sizeof(int), stream);
    hipMemsetAsync(pos, 0, N * sizeof(int), stream);
    hipMemsetAsync(sums, 0, NG * 64 * sizeof(float), stream);
    hipMemsetAsync(cnt, 0, NG * sizeof(int), stream);

    // weight prep
    PrepArgs p;
    p.w1[0] = w1_0; p.w2[0] = w2_0; p.b1[0] = b1_0; p.ig[0] = ig0; p.ib[0] = ib0;
    p.im[0] = im0; p.iv[0] = iv0; p.b2[0] = b2_0;
    for (int i = 1; i < 5; ++i) {
        p.w1[i] = W1s + (size_t)(i - 1) * 64 * 128;
        p.w2[i] = W2s + (size_t)(i - 1) * 128 * 64;
        p.b1[i] = b1s + (i - 1) * 128;
        p.ig[i] = IG + (i - 1) * 128; p.ib[i] = IB + (i - 1) * 128;
        p.im[i] = IM + (i - 1) * 128; p.iv[i] = IV + (i - 1) * 128;
        p.b2[i] = b2s + (i - 1) * 64;
    }
    p.og = OG; p.ob = OB; p.om = OM; p.ov = OV;
    p.w1t[0] = w1t;
    for (int i = 1; i < 5; ++i) p.w1t[i] = w1t + 16384 + (size_t)(i - 1) * 8192;
    for (int i = 0; i < 5; ++i) {
        p.w2t[i] = w2t + (size_t)i * 8192;
        p.s1[i] = s1 + i * 128; p.c1[i] = c1 + i * 128;
        p.s2[i] = s2 + i * 64;  p.c2[i] = c2 + i * 64;
    }
    prep_kernel<<<5, 256, 0, stream>>>(p);

    // CSR build (edge_index layer-invariant)
    hist_kernel<<<EB, 256, 0, stream>>>(dst, deg, E);
    scan1_kernel<<<NB, 256, 0, stream>>>(deg, row_ptr, blocksum, N);
    scan2_kernel<<<1, 256, 0, stream>>>(blocksum, NB);
    scan3_kernel<<<NB, 256, 0, stream>>>(row_ptr, blocksum, N);
    fill_kernel<<<EB, 256, 0, stream>>>(src, dst, row_ptr, pos, col, E);

    const int MGB = (N + 63) / 64;    // 782

    // layer 0
    agg0_kernel<<<(N + 3) / 4, 256, 0, stream>>>(x, row_ptr, col, ybuf, N);
    mlp_mfma<128><<<MGB, 256, 0, stream>>>(ybuf, hbuf, p.w1t[0], p.w2t[0],
                                           p.s1[0], p.c1[0], p.s2[0], p.c2[0], N);
    // layers 1..4
    for (int i = 1; i < 5; ++i) {
        agg1_kernel<<<(N + 7) / 8, 256, 0, stream>>>(hbuf, row_ptr, col, ybuf, N);
        mlp_mfma<64><<<MGB, 256, 0, stream>>>(ybuf, hbuf, p.w1t[i], p.w2t[i],
                                              p.s1[i], p.c1[i], p.s2[i], p.c2[i], N);
    }

    pool_kernel<<<NB, 32, 0, stream>>>(hbuf, batch, sums, cnt, N);
    finalize_kernel<<<32, 256, 0, stream>>>(sums, cnt, out);
}

// Round 3
// 527.764 us; speedup vs baseline: 1.4672x; 1.0925x over previous
//
#include <hip/hip_runtime.h>
#include <stdint.h>

#define NN 50000
#define NE 800000
#define NG 128
#define BN_EPS 1e-5f

typedef __attribute__((ext_vector_type(8))) __bf16 bf16x8;
typedef __attribute__((ext_vector_type(8))) unsigned short ushort8;
typedef __attribute__((ext_vector_type(4))) float floatx4;

__device__ inline unsigned short f2bf(float f) {
    union { float f; unsigned u; } x; x.f = f;
    unsigned u = x.u;
    return (unsigned short)((u + 0x7fffu + ((u >> 16) & 1u)) >> 16);
}
__device__ inline float bflo(unsigned u) {
    union { unsigned u; float f; } x; x.u = u << 16; return x.f;
}
__device__ inline float bfhi(unsigned u) {
    union { unsigned u; float f; } x; x.u = u & 0xffff0000u; return x.f;
}
__device__ inline unsigned pack_bf2(float a, float b) {
    union { struct { __bf16 x, y; } s; unsigned u; } t;
    t.s.x = (__bf16)a; t.s.y = (__bf16)b; return t.u;
}
__device__ inline bf16x8 as_bf(ushort8 u) {
    union { ushort8 u; bf16x8 b; } x; x.u = u; return x.b;
}

// ---------------- CSR build ----------------

__global__ void hist_kernel(const int* __restrict__ dst, int* __restrict__ deg, int E) {
    int e = blockIdx.x * 256 + threadIdx.x;
    if (e < E) atomicAdd(&deg[dst[e]], 1);
}

__global__ void scan1_kernel(const int* __restrict__ deg, int* __restrict__ row_ptr,
                             int* __restrict__ blocksum, int n) {
    __shared__ int s[256];
    int i = blockIdx.x * 256 + threadIdx.x;
    int v = (i < n) ? deg[i] : 0;
    s[threadIdx.x] = v;
    __syncthreads();
    for (int off = 1; off < 256; off <<= 1) {
        int t = (threadIdx.x >= off) ? s[threadIdx.x - off] : 0;
        __syncthreads();
        s[threadIdx.x] += t;
        __syncthreads();
    }
    if (i < n) row_ptr[i + 1] = s[threadIdx.x];
    if (threadIdx.x == 255) blocksum[blockIdx.x] = s[255];
}

__global__ void scan2_kernel(int* __restrict__ blocksum, int nb) {
    __shared__ int s[256];
    int v = (threadIdx.x < nb) ? blocksum[threadIdx.x] : 0;
    s[threadIdx.x] = v;
    __syncthreads();
    for (int off = 1; off < 256; off <<= 1) {
        int t = (threadIdx.x >= off) ? s[threadIdx.x - off] : 0;
        __syncthreads();
        s[threadIdx.x] += t;
        __syncthreads();
    }
    if (threadIdx.x < nb) blocksum[threadIdx.x] = s[threadIdx.x] - v;
}

__global__ void scan3_kernel(int* __restrict__ row_ptr, const int* __restrict__ blocksum, int n) {
    int i = blockIdx.x * 256 + threadIdx.x;
    if (i < n) row_ptr[i + 1] += blocksum[blockIdx.x];
    if (i == 0) row_ptr[0] = 0;
}

__global__ void fill_kernel(const int* __restrict__ src, const int* __restrict__ dst,
                            const int* __restrict__ row_ptr, int* __restrict__ pos,
                            int* __restrict__ col, int E) {
    int e = blockIdx.x * 256 + threadIdx.x;
    if (e < E) {
        int d = dst[e];
        int p = atomicAdd(&pos[d], 1);
        col[row_ptr[d] + p] = src[e];
    }
}

// ---------------- weight prep ----------------

struct PrepArgs {
    const float* w1[5]; const float* w2[5];
    const float* b1[5]; const float* ig[5]; const float* ib[5];
    const float* im[5]; const float* iv[5]; const float* b2[5];
    const float* og; const float* ob; const float* om; const float* ov;
    unsigned short* w1t[5]; unsigned short* w2t[5];
    float* s1[5]; float* c1[5]; float* s2[5]; float* c2[5];
};

__global__ void prep_kernel(PrepArgs p) {
    int layer = blockIdx.x;
    int K = (layer == 0) ? 128 : 64;
    int kshift = (layer == 0) ? 7 : 6;
    const float* w1 = p.w1[layer];
    unsigned short* w1t = p.w1t[layer];
    for (int idx = threadIdx.x; idx < 128 * K; idx += blockDim.x) {
        int c = idx >> kshift, k = idx & (K - 1);
        w1t[idx] = f2bf(w1[k * 128 + c]);
    }
    const float* w2 = p.w2[layer];
    unsigned short* w2t = p.w2t[layer];
    for (int idx = threadIdx.x; idx < 64 * 128; idx += blockDim.x) {
        int c = idx >> 7, k = idx & 127;
        w2t[idx] = f2bf(w2[k * 64 + c]);
    }
    if (threadIdx.x < 128) {
        int ch = threadIdx.x;
        float s = p.ig[layer][ch] * rsqrtf(p.iv[layer][ch] + BN_EPS);
        p.s1[layer][ch] = s;
        p.c1[layer][ch] = (p.b1[layer][ch] - p.im[layer][ch]) * s + p.ib[layer][ch];
        if (ch < 64) {
            float s2v = p.og[layer * 64 + ch] * rsqrtf(p.ov[layer * 64 + ch] + BN_EPS);
            p.s2[layer][ch] = s2v;
            p.c2[layer][ch] = (p.b2[layer][ch] - p.om[layer * 64 + ch]) * s2v + p.ob[layer * 64 + ch];
        }
    }
}

// ---------------- x fp32 -> bf16 (streaming) ----------------

__global__ void xcvt_kernel(const float* __restrict__ x, unsigned* __restrict__ xb, int npair) {
    int i = blockIdx.x * 256 + threadIdx.x;
    if (i < npair) {
        float2 v = ((const float2*)x)[i];
        xb[i] = pack_bf2(v.x, v.y);
    }
}

// ---------------- aggregation ----------------

// layer 0: xb bf16 [N][128] -> y bf16 [N][128]; wave per node, lane = ch-pair
__global__ void agg0_kernel(const unsigned* __restrict__ xb, const int* __restrict__ rp,
                            const int* __restrict__ col, unsigned* __restrict__ y, int n) {
    int node = blockIdx.x * 4 + (threadIdx.x >> 6);
    int l = threadIdx.x & 63;
    if (node >= n) return;
    unsigned u = xb[(size_t)node * 64 + l];
    float a0 = bflo(u), a1 = bfhi(u);
    int beg = rp[node], end = rp[node + 1];
    int e = beg;
    for (; e + 2 <= end; e += 2) {
        unsigned v0 = xb[(size_t)col[e] * 64 + l];
        unsigned v1 = xb[(size_t)col[e + 1] * 64 + l];
        a0 += bflo(v0); a1 += bfhi(v0);
        a0 += bflo(v1); a1 += bfhi(v1);
    }
    if (e < end) { unsigned v = xb[(size_t)col[e] * 64 + l]; a0 += bflo(v); a1 += bfhi(v); }
    y[(size_t)node * 64 + l] = pack_bf2(a0, a1);
}

// layers 1..4: h bf16 [N][64] -> y bf16 [N][64]; half-wave per node
__global__ void agg1_kernel(const unsigned short* __restrict__ h, const int* __restrict__ rp,
                            const int* __restrict__ col, unsigned short* __restrict__ y, int n) {
    int node = blockIdx.x * 8 + (threadIdx.x >> 5);
    int l = threadIdx.x & 31;
    if (node >= n) return;
    const unsigned* hr = (const unsigned*)h;
    unsigned u = hr[(size_t)node * 32 + l];
    float a0 = bflo(u), a1 = bfhi(u);
    int beg = rp[node], end = rp[node + 1];
    int e = beg;
    for (; e + 2 <= end; e += 2) {
        unsigned v0 = hr[(size_t)col[e] * 32 + l];
        unsigned v1 = hr[(size_t)col[e + 1] * 32 + l];
        a0 += bflo(v0); a1 += bfhi(v0);
        a0 += bflo(v1); a1 += bfhi(v1);
    }
    if (e < end) { unsigned v = hr[(size_t)col[e] * 32 + l]; a0 += bflo(v); a1 += bfhi(v); }
    ((unsigned*)y)[(size_t)node * 32 + l] = pack_bf2(a0, a1);
}

// ---------------- fused MLP via MFMA ----------------

template <int K>
__launch_bounds__(256, 3)
__global__ void mlp_mfma(const unsigned short* __restrict__ yb, unsigned short* __restrict__ hb,
                         const unsigned short* __restrict__ w1t,  // [128][K] bf16
                         const unsigned short* __restrict__ w2t,  // [64][128] bf16
                         const float* __restrict__ s1, const float* __restrict__ c1,
                         const float* __restrict__ s2, const float* __restrict__ c2,
                         int n) {
    __shared__ float zl[64 * 132];
    const int tid = threadIdx.x;
    const int w = tid >> 6;
    const int l = tid & 63;
    const int l15 = l & 15, lg = l >> 4;
    const int node0 = blockIdx.x * 64;

    // ---- GEMM1: Z[64x128] = Y[64xK] @ W1[Kx128]
    const int arow = node0 + w * 16 + l15;
    const int arow_c = min(arow, n - 1);
    bf16x8 afr[K / 32];
#pragma unroll
    for (int ks = 0; ks < K / 32; ++ks)
        afr[ks] = as_bf(*(const ushort8*)(yb + (size_t)arow_c * K + ks * 32 + lg * 8));

#pragma unroll
    for (int cc = 0; cc < 8; ++cc) {
        floatx4 acc = {0.f, 0.f, 0.f, 0.f};
#pragma unroll
        for (int ks = 0; ks < K / 32; ++ks) {
            bf16x8 bfr = as_bf(*(const ushort8*)(w1t + (size_t)(cc * 16 + l15) * K + ks * 32 + lg * 8));
            acc = __builtin_amdgcn_mfma_f32_16x16x32_bf16(afr[ks], bfr, acc, 0, 0, 0);
        }
        int ch = cc * 16 + l15;
        float s = s1[ch], c = c1[ch];
#pragma unroll
        for (int r = 0; r < 4; ++r) {
            int row = w * 16 + lg * 4 + r;
            zl[row * 132 + ch] = fmaxf(acc[r] * s + c, 0.f);
        }
    }
    __syncthreads();

    // ---- GEMM2: H[64x64] = Zr[64x128] @ W2[128x64]
    floatx4 acc2[4];
#pragma unroll
    for (int ct = 0; ct < 4; ++ct) acc2[ct] = (floatx4){0.f, 0.f, 0.f, 0.f};

#pragma unroll
    for (int ks = 0; ks < 4; ++ks) {
        const float* zp = &zl[(w * 16 + l15) * 132 + ks * 32 + lg * 8];
        float4 za = *(const float4*)zp;
        float4 zb = *(const float4*)(zp + 4);
        bf16x8 a2;
        a2[0] = (__bf16)za.x; a2[1] = (__bf16)za.y; a2[2] = (__bf16)za.z; a2[3] = (__bf16)za.w;
        a2[4] = (__bf16)zb.x; a2[5] = (__bf16)zb.y; a2[6] = (__bf16)zb.z; a2[7] = (__bf16)zb.w;
#pragma unroll
        for (int ct = 0; ct < 4; ++ct) {
            bf16x8 b2 = as_bf(*(const ushort8*)(w2t + (size_t)(ct * 16 + l15) * 128 + ks * 32 + lg * 8));
            acc2[ct] = __builtin_amdgcn_mfma_f32_16x16x32_bf16(a2, b2, acc2[ct], 0, 0, 0);
        }
    }
    __syncthreads();

    // ---- BN2 + ReLU -> per-wave H region (stride 68), then coalesced bf16 store
    float* Hp = zl + w * 2112;
#pragma unroll
    for (int ct = 0; ct < 4; ++ct) {
        int ch = ct * 16 + l15;
        float s = s2[ch], c = c2[ch];
#pragma unroll
        for (int r = 0; r < 4; ++r)
            Hp[(lg * 4 + r) * 68 + ch] = fmaxf(acc2[ct][r] * s + c, 0.f);
    }
    __syncthreads();

    int nr = l >> 2, ch0 = (l & 3) * 16;
    int node = node0 + w * 16 + nr;
    if (node < n) {
        const float* q = Hp + nr * 68 + ch0;
        ushort8 u0, u1;
#pragma unroll
        for (int j = 0; j < 8; ++j) { union { __bf16 b; unsigned short s; } t; t.b = (__bf16)q[j]; u0[j] = t.s; }
#pragma unroll
        for (int j = 0; j < 8; ++j) { union { __bf16 b; unsigned short s; } t; t.b = (__bf16)q[8 + j]; u1[j] = t.s; }
        *(ushort8*)(hb + (size_t)node * 64 + ch0) = u0;
        *(ushort8*)(hb + (size_t)node * 64 + ch0 + 8) = u1;
    }
}

// ---------------- pooling (batch sorted): half-wave per 32 nodes ----------------

__global__ void pool_kernel(const unsigned short* __restrict__ h, const int* __restrict__ batch,
                            float* __restrict__ sums, int* __restrict__ cnt, int n) {
    int hw = (blockIdx.x * 256 + threadIdx.x) >> 5;
    int l = threadIdx.x & 31;
    int n0 = hw * 32;
    if (n0 >= n) return;
    int n1 = min(n0 + 32, n);
    const unsigned* hr = (const unsigned*)h;
    float a0 = 0.f, a1 = 0.f; int c = 0;
    int g_cur = batch[n0];
    for (int i = n0; i < n1; ++i) {
        int g = batch[i];
        if (g != g_cur) {
            atomicAdd(&sums[g_cur * 64 + 2 * l], a0);
            atomicAdd(&sums[g_cur * 64 + 2 * l + 1], a1);
            if (l == 0) atomicAdd(&cnt[g_cur], c);
            a0 = a1 = 0.f; c = 0; g_cur = g;
        }
        unsigned u = hr[(size_t)i * 32 + l];
        a0 += bflo(u); a1 += bfhi(u);
        c++;
    }
    atomicAdd(&sums[g_cur * 64 + 2 * l], a0);
    atomicAdd(&sums[g_cur * 64 + 2 * l + 1], a1);
    if (l == 0) atomicAdd(&cnt[g_cur], c);
}

__global__ void finalize_kernel(const float* __restrict__ sums, const int* __restrict__ cnt,
                                float* __restrict__ out) {
    int i = blockIdx.x * 256 + threadIdx.x;
    if (i < NG * 64) {
        float c = (float)cnt[i >> 6];
        out[i] = sums[i] / fmaxf(c, 1.f);
    }
}

// ---------------- launcher ----------------

extern "C" void kernel_launch(void* const* d_in, const int* in_sizes, int n_in,
                              void* d_out, int out_size, void* d_ws, size_t ws_size,
                              hipStream_t stream) {
    const float* x    = (const float*)d_in[0];
    const int*  ei    = (const int*)d_in[1];
    const int*  batch = (const int*)d_in[2];
    const float* w1_0 = (const float*)d_in[3];
    const float* b1_0 = (const float*)d_in[4];
    const float* ig0  = (const float*)d_in[5];
    const float* ib0  = (const float*)d_in[6];
    const float* im0  = (const float*)d_in[7];
    const float* iv0  = (const float*)d_in[8];
    const float* w2_0 = (const float*)d_in[9];
    const float* b2_0 = (const float*)d_in[10];
    const float* W1s  = (const float*)d_in[11];
    const float* b1s  = (const float*)d_in[12];
    const float* IG   = (const float*)d_in[13];
    const float* IB   = (const float*)d_in[14];
    const float* IM   = (const float*)d_in[15];
    const float* IV   = (const float*)d_in[16];
    const float* W2s  = (const float*)d_in[17];
    const float* b2s  = (const float*)d_in[18];
    const float* OG   = (const float*)d_in[19];
    const float* OB   = (const float*)d_in[20];
    const float* OM   = (const float*)d_in[21];
    const float* OV   = (const float*)d_in[22];
    float* out = (float*)d_out;

    const int N = NN, E = NE;
    const int* src = ei;
    const int* dst = ei + E;

    char* ws = (char*)d_ws;
    size_t off = 0;
    auto alloc = [&](size_t bytes) -> void* {
        void* p = ws + off;
        off += (bytes + 255) & ~(size_t)255;
        return p;
    };
    int*   row_ptr  = (int*)alloc((N + 1) * sizeof(int));
    int*   deg      = (int*)alloc(N * sizeof(int));
    int*   pos      = (int*)alloc(N * sizeof(int));
    int*   blocksum = (int*)alloc(256 * sizeof(int));
    int*   col      = (int*)alloc((size_t)E * sizeof(int));
    unsigned* xb    = (unsigned*)alloc((size_t)N * 64 * 4);
    unsigned short* ybuf = (unsigned short*)alloc((size_t)N * 128 * 2);
    unsigned short* hbuf = (unsigned short*)alloc((size_t)N * 64 * 2);
    unsigned short* w1t  = (unsigned short*)alloc(49152 * 2);
    unsigned short* w2t  = (unsigned short*)alloc(5 * 64 * 128 * 2);
    float* s1 = (float*)alloc(5 * 128 * sizeof(float));
    float* c1 = (float*)alloc(5 * 128 * sizeof(float));
    float* s2 = (float*)alloc(5 * 64 * sizeof(float));
    float* c2 = (float*)alloc(5 * 64 * sizeof(float));
    float* sums = (float*)alloc(NG * 64 * sizeof(float));
    int*   cnt  = (int*)alloc(NG * sizeof(int));

    const int NB = (N + 255) / 256;
    const int EB = (E + 255) / 256;

    hipMemsetAsync(deg, 0, N * sizeof(int), stream);
    hipMemsetAsync(pos, 0, N * sizeof(int), stream);
    hipMemsetAsync(sums, 0, NG * 64 * sizeof(float), stream);
    hipMemsetAsync(cnt, 0, NG * sizeof(int), stream);

    PrepArgs p;
    p.w1[0] = w1_0; p.w2[0] = w2_0; p.b1[0] = b1_0; p.ig[0] = ig0; p.ib[0] = ib0;
    p.im[0] = im0; p.iv[0] = iv0; p.b2[0] = b2_0;
    for (int i = 1; i < 5; ++i) {
        p.w1[i] = W1s + (size_t)(i - 1) * 64 * 128;
        p.w2[i] = W2s + (size_t)(i - 1) * 128 * 64;
        p.b1[i] = b1s + (i - 1) * 128;
        p.ig[i] = IG + (i - 1) * 128; p.ib[i] = IB + (i - 1) * 128;
        p.im[i] = IM + (i - 1) * 128; p.iv[i] = IV + (i - 1) * 128;
        p.b2[i] = b2s + (i - 1) * 64;
    }
    p.og = OG; p.ob = OB; p.om = OM; p.ov = OV;
    p.w1t[0] = w1t;
    for (int i = 1; i < 5; ++i) p.w1t[i] = w1t + 16384 + (size_t)(i - 1) * 8192;
    for (int i = 0; i < 5; ++i) {
        p.w2t[i] = w2t + (size_t)i * 8192;
        p.s1[i] = s1 + i * 128; p.c1[i] = c1 + i * 128;
        p.s2[i] = s2 + i * 64;  p.c2[i] = c2 + i * 64;
    }
    prep_kernel<<<5, 256, 0, stream>>>(p);

    hist_kernel<<<EB, 256, 0, stream>>>(dst, deg, E);
    scan1_kernel<<<NB, 256, 0, stream>>>(deg, row_ptr, blocksum, N);
    scan2_kernel<<<1, 256, 0, stream>>>(blocksum, NB);
    scan3_kernel<<<NB, 256, 0, stream>>>(row_ptr, blocksum, N);
    fill_kernel<<<EB, 256, 0, stream>>>(src, dst, row_ptr, pos, col, E);

    xcvt_kernel<<<(N * 64 + 255) / 256, 256, 0, stream>>>(x, xb, N * 64);

    const int MGB = (N + 63) / 64;

    agg0_kernel<<<(N + 3) / 4, 256, 0, stream>>>(xb, row_ptr, col, (unsigned*)ybuf, N);
    mlp_mfma<128><<<MGB, 256, 0, stream>>>(ybuf, hbuf, p.w1t[0], p.w2t[0],
                                           p.s1[0], p.c1[0], p.s2[0], p.c2[0], N);
    for (int i = 1; i < 5; ++i) {
        agg1_kernel<<<(N + 7) / 8, 256, 0, stream>>>(hbuf, row_ptr, col, ybuf, N);
        mlp_mfma<64><<<MGB, 256, 0, stream>>>(ybuf, hbuf, p.w1t[i], p.w2t[i],
                                              p.s1[i], p.c1[i], p.s2[i], p.c2[i], N);
    }

    pool_kernel<<<NB, 256, 0, stream>>>(hbuf, batch, sums, cnt, N);
    finalize_kernel<<<32, 256, 0, stream>>>(sums, cnt, out);
}